// Round 1
// baseline (99.491 us; speedup 1.0000x reference)
//
#include <hip/hip_runtime.h>

// Closing = erosion(identity-merge) ∘ dilation(sum-merge), K=5, edge padding.
// Fused single kernel: per (b, o, 32x32 tile) block.
//   LDS: x halo tile 3x40x40 (clamp folded into load), dilated tile 36x36.
//   Each thread: dilation quads (4 cols) over 324 tasks, then 4 erosion outputs.

namespace {
constexpr int Hh = 256, Ww = 256;
constexpr int CI = 3, CO = 16;
constexpr int TILE = 32;   // output tile
constexpr int DT = 36;     // dilated tile (TILE + 4)
constexpr int XT = 40;     // x halo tile (TILE + 8)
}

__global__ __launch_bounds__(256, 4)
void closing_fused(const float* __restrict__ x, const float* __restrict__ wd,
                   const float* __restrict__ we, float* __restrict__ out) {
    __shared__ __align__(16) float sx[CI * XT * XT];   // 19200 B
    __shared__ __align__(16) float sdil[DT * DT];      //  5184 B

    const int tid = threadIdx.x;
    const int bx = blockIdx.x, by = blockIdx.y, z = blockIdx.z;
    const int o = z & 15;           // z = b*COUT + o
    const int i0 = by * TILE, j0 = bx * TILE;

    const float* xb  = x + (size_t)(z >> 4) * (CI * Hh * Ww);
    const float* wdo = wd + o * (CI * 25);   // block-uniform -> s_load
    const float* weo = we + o * 25;

    // ---- stage x halo tile, edge clamp folded in ----
    for (int idx = tid; idx < CI * XT * XT; idx += 256) {
        const int c   = idx / (XT * XT);
        const int rem = idx - c * (XT * XT);
        const int r   = rem / XT;
        const int col = rem - r * XT;
        int gi = i0 - 4 + r;   gi = min(max(gi, 0), Hh - 1);
        int gj = j0 - 4 + col; gj = min(max(gj, 0), Ww - 1);
        sx[idx] = xb[c * (Hh * Ww) + gi * Ww + gj];
    }
    __syncthreads();

    // ---- dilation: 36x36 tile, 9 quads/row * 36 rows = 324 quad tasks ----
    // dil[ti][tj] = sum_c max_{dd,d2} sx[c][ti+dd][tj+d2] + wd[o][c][dd][d2]
    for (int task = tid; task < DT * (DT / 4); task += 256) {
        const int tr = task / 9;
        const int tj = (task - tr * 9) * 4;
        float acc0 = 0.f, acc1 = 0.f, acc2 = 0.f, acc3 = 0.f;
#pragma unroll
        for (int c = 0; c < CI; ++c) {
            float win[5][8];
#pragma unroll
            for (int dd = 0; dd < 5; ++dd) {
                const float4 a  = *(const float4*)&sx[c*(XT*XT) + (tr+dd)*XT + tj];
                const float4 bq = *(const float4*)&sx[c*(XT*XT) + (tr+dd)*XT + tj + 4];
                win[dd][0]=a.x;  win[dd][1]=a.y;  win[dd][2]=a.z;  win[dd][3]=a.w;
                win[dd][4]=bq.x; win[dd][5]=bq.y; win[dd][6]=bq.z; win[dd][7]=bq.w;
            }
            float m0 = -3.402823e38f, m1 = m0, m2 = m0, m3 = m0;
#pragma unroll
            for (int dd = 0; dd < 5; ++dd) {
#pragma unroll
                for (int d2 = 0; d2 < 5; ++d2) {
                    const float wv = wdo[c*25 + dd*5 + d2];
                    m0 = fmaxf(m0, win[dd][d2+0] + wv);
                    m1 = fmaxf(m1, win[dd][d2+1] + wv);
                    m2 = fmaxf(m2, win[dd][d2+2] + wv);
                    m3 = fmaxf(m3, win[dd][d2+3] + wv);
                }
            }
            acc0 += m0; acc1 += m1; acc2 += m2; acc3 += m3;
        }
        *(float4*)&sdil[tr * DT + tj] = make_float4(acc0, acc1, acc2, acc3);
    }
    __syncthreads();

    // ---- erosion: 32x32 outputs, 4 consecutive cols per thread ----
    const int r  = tid >> 3;
    const int oj = (tid & 7) * 4;
    float win[5][8];
    const bool interior = (bx != 0) & (bx != (Ww / TILE - 1)) &
                          (by != 0) & (by != (Hh / TILE - 1));
    if (interior) {
#pragma unroll
        for (int dd = 0; dd < 5; ++dd) {
            const float4 a  = *(const float4*)&sdil[(r+dd)*DT + oj];
            const float4 bq = *(const float4*)&sdil[(r+dd)*DT + oj + 4];
            win[dd][0]=a.x;  win[dd][1]=a.y;  win[dd][2]=a.z;  win[dd][3]=a.w;
            win[dd][4]=bq.x; win[dd][5]=bq.y; win[dd][6]=bq.z; win[dd][7]=bq.w;
        }
    } else {
        int lj[8];
#pragma unroll
        for (int m = 0; m < 8; ++m) {
            int g = j0 + oj + m - 2; g = min(max(g, 0), Ww - 1);
            lj[m] = g - j0 + 2;      // local col into sdil
        }
#pragma unroll
        for (int dd = 0; dd < 5; ++dd) {
            int g = i0 + r + dd - 2; g = min(max(g, 0), Hh - 1);
            const int li = g - i0 + 2;
#pragma unroll
            for (int m = 0; m < 8; ++m) win[dd][m] = sdil[li * DT + lj[m]];
        }
    }
    float r0 = 3.402823e38f, r1 = r0, r2 = r0, r3 = r0;
#pragma unroll
    for (int dd = 0; dd < 5; ++dd) {
#pragma unroll
        for (int d2 = 0; d2 < 5; ++d2) {
            const float wv = weo[dd*5 + d2];
            r0 = fminf(r0, win[dd][d2+0] - wv);
            r1 = fminf(r1, win[dd][d2+1] - wv);
            r2 = fminf(r2, win[dd][d2+2] - wv);
            r3 = fminf(r3, win[dd][d2+3] - wv);
        }
    }
    *(float4*)&out[((size_t)z << 16) + ((i0 + r) << 8) + (j0 + oj)] =
        make_float4(r0, r1, r2, r3);
}

extern "C" void kernel_launch(void* const* d_in, const int* in_sizes, int n_in,
                              void* d_out, int out_size, void* d_ws, size_t ws_size,
                              hipStream_t stream) {
    const float* x  = (const float*)d_in[0];   // (4,3,256,256)
    const float* wd = (const float*)d_in[1];   // (16,3,5,5)
    const float* we = (const float*)d_in[2];   // (16,5,5)
    float* out = (float*)d_out;                // (4,16,256,256)

    dim3 grid(Ww / TILE, Hh / TILE, 4 * CO);   // (8, 8, 64)
    closing_fused<<<grid, dim3(256), 0, stream>>>(x, wd, we, out);
}